// Round 11
// baseline (55.350 us; speedup 1.0000x reference)
//
#include <hip/hip_runtime.h>
#include <hip/hip_fp16.h>
#include <cstddef>
#include <cstdint>

#define D_IN  4096
#define D_OUT 4096
#define BB    64
#define NBLK  64    // bin blocks, block-private stripes
#define PPB   4096  // points per bin block (NBLK*PPB >= N)
#define CAP   24    // slots per (col,blk) cell: mean 1, P(Poisson(1)>24)~1e-24

// ws layout:
//   [bins:    NBLK*D_OUT*CAP*8B  = 50.3MB]
//   [cellCnt: NBLK*D_OUT*4B      = 1MB]
//   [xP:      D_IN*BB*8B         = 2MB]
//   [accT:    D_OUT*BB*4B        = 1MB]
//   [accN:    D_OUT*BB*4B        = 1MB]
// Block-private counting sort: ZERO global returning atomics, no scan pass.
// Entry (8B):
//   .x: rowf[0:11] | rint<<12 | f16(wfr)<<16
//   .y: f16(w_this) | f16(w_next)<<16
// rowc = rowf+1-rint, wcr = rint ? 1 : 1-wfr,
// w_this = v*wfc (+ v*wcc if integer col), w_next = v*wcc (0 if integer col).
// xP[row][b] = (x[row][b], x[row+1][b]).
// out[c,:] = accT[c,:] + accN[c-1,:],
//   accT[c] = sum entries keyed c: w_this*term, accN[c] = w_next*term,
//   term = wfr*x[rowf,:] + wcr*x[rowc,:] (integer row -> 2*x[rowf], matches ref).

// ---------------------------------------------------------------------------
// K1: blocks 0..63: bin points into private stripes, rank via LDS atomic.
//     blocks 64.. : build xP pair table.
// ---------------------------------------------------------------------------
__global__ __launch_bounds__(256) void binprep_kernel(
    const float2* __restrict__ ind, const float* __restrict__ val,
    const float* __restrict__ x, uint2* __restrict__ bins,
    uint32_t* __restrict__ cellCnt, float2* __restrict__ xP, int n) {
  const int blk = blockIdx.x;
  if (blk >= NBLK) {
    int i = (blk - NBLK) * 256 + threadIdx.x;   // 0 .. D_IN*BB-1
    if (i < D_IN * BB) {
      float a = x[i];
      float bq = (i + BB < D_IN * BB) ? x[i + BB] : 0.f;
      xP[i] = make_float2(a, bq);
    }
    return;
  }
  __shared__ uint32_t lcnt[D_OUT];
  const int tid = threadIdx.x;
  for (int c = tid; c < D_OUT; c += 256) lcnt[c] = 0u;
  __syncthreads();
  const int base = blk * PPB;
#pragma unroll
  for (int i = 0; i < PPB / 256; i++) {
    int p = base + i * 256 + tid;
    if (p >= n) continue;
    float2 rc = ind[p];
    float v = val[p];
    float flr = floorf(rc.x), cer = ceilf(rc.x);
    float flc = floorf(rc.y), cec = ceilf(rc.y);
    // reference weight: prod_k (1 - |corner_k - ind_k|)
    float wfr = 1.0f - (rc.x - flr);
    float wfc = 1.0f - (rc.y - flc);
    float wcc = 1.0f - (cec - rc.y);
    uint32_t rint = ((int)flr == (int)cer) ? 1u : 0u;
    bool cint = ((int)flc == (int)cec);
    float w_this = cint ? v * (wfc + wcc) : v * wfc;
    float w_next = cint ? 0.f : v * wcc;
    uint32_t ex = (uint32_t)(int)flr | (rint << 12)
                | ((uint32_t)__half_as_ushort(__float2half_rn(wfr)) << 16);
    uint32_t ey = (uint32_t)__half_as_ushort(__float2half_rn(w_this))
                | ((uint32_t)__half_as_ushort(__float2half_rn(w_next)) << 16);
    int key = (int)flc;
    uint32_t rank = atomicAdd(&lcnt[key], 1u);   // LDS returning atomic (fast)
    if (rank < CAP)
      bins[((size_t)blk * D_OUT + key) * CAP + rank] = make_uint2(ex, ey);
  }
  __syncthreads();
  for (int c = tid; c < D_OUT; c += 256) {
    uint32_t vv = lcnt[c];
    cellCnt[(size_t)blk * D_OUT + c] = vv < CAP ? vv : CAP;
  }
}

// ---------------------------------------------------------------------------
// K2: one block (4 waves) per column, lane = b. Wave wv scans 16 block-cells;
// counts prefetched (uniform s_loads), entries broadcast 8B loads, xP gather
// coalesced 512B. Non-atomic partial outputs accT/accN (no zeroing needed).
// ---------------------------------------------------------------------------
__global__ __launch_bounds__(256) void accum_kernel(
    const uint32_t* __restrict__ cellCnt, const uint2* __restrict__ bins,
    const float2* __restrict__ xP, float* __restrict__ accT,
    float* __restrict__ accN) {
  __shared__ float red_t[3][BB], red_n[3][BB];
  const int lane = threadIdx.x & 63;
  const int wv   = threadIdx.x >> 6;   // 0..3
  const int col  = blockIdx.x;

  float acc_t = 0.f, acc_n = 0.f;

  // prefetch the 16 cell counts (wave-uniform addresses -> scalar loads)
  uint32_t cnts[NBLK / 4];
#pragma unroll
  for (int bq = 0; bq < NBLK / 4; bq++)
    cnts[bq] = cellCnt[(size_t)(wv * (NBLK / 4) + bq) * D_OUT + col];

#define PROC(Q)                                                           \
  {                                                                       \
    uint32_t ex_ = (Q).x, ey_ = (Q).y;                                    \
    int rowf = (int)(ex_ & 0xfffu);                                       \
    int rint = (int)((ex_ >> 12) & 1u);                                   \
    float wfr = __half2float(__ushort_as_half((ushort)(ex_ >> 16)));      \
    float2 p  = xP[(size_t)rowf * BB + lane];                             \
    float xc  = rint ? p.x : p.y;                                         \
    float wcr = rint ? 1.0f : 1.0f - wfr;                                 \
    float w_t = __half2float(__ushort_as_half((ushort)(ey_ & 0xffffu)));  \
    float w_n = __half2float(__ushort_as_half((ushort)(ey_ >> 16)));      \
    float term = fmaf(wfr, p.x, wcr * xc);                                \
    acc_t = fmaf(w_t, term, acc_t);                                       \
    acc_n = fmaf(w_n, term, acc_n);                                       \
  }

#pragma unroll 4
  for (int bq = 0; bq < NBLK / 4; bq++) {
    const int blk = wv * (NBLK / 4) + bq;
    const int cnt = (int)cnts[bq];
    const uint2* __restrict__ cell =
        bins + ((size_t)blk * D_OUT + col) * CAP;
    for (int e = 0; e < cnt; e++) {     // wave-uniform trip count: no divergence
      uint2 q = cell[e];
      PROC(q)
    }
  }
#undef PROC

  if (wv > 0) {
    red_t[wv - 1][lane] = acc_t;
    red_n[wv - 1][lane] = acc_n;
  }
  __syncthreads();
  if (wv == 0) {
    acc_t += red_t[0][lane] + red_t[1][lane] + red_t[2][lane];
    acc_n += red_n[0][lane] + red_n[1][lane] + red_n[2][lane];
    accT[(size_t)col * BB + lane] = acc_t;   // non-atomic, full overwrite
    accN[(size_t)col * BB + lane] = acc_n;
  }
}

// ---------------------------------------------------------------------------
// K3: out[c,:] = accT[c,:] + accN[c-1,:]
// ---------------------------------------------------------------------------
__global__ __launch_bounds__(256) void combine_kernel(
    const float* __restrict__ accT, const float* __restrict__ accN,
    float* __restrict__ out) {
  int i = blockIdx.x * 256 + threadIdx.x;   // 0 .. D_OUT*BB-1
  float r = accT[i];
  if (i >= BB) r += accN[i - BB];
  out[i] = r;
}

// ---------------------------------------------------------------------------
// Fallback (ws too small / N too big): direct atomic scatter into out (f32).
// ---------------------------------------------------------------------------
__global__ __launch_bounds__(256) void direct_kernel(
    const float2* __restrict__ ind, const float* __restrict__ val,
    const float* __restrict__ x, float* __restrict__ out, int n) {
  int p = blockIdx.x * 4 + (threadIdx.x >> 6);
  if (p >= n) return;
  int lane = threadIdx.x & 63;
  float2 rc = ind[p];
  float v = val[p];
  float flr = floorf(rc.x), cer = ceilf(rc.x);
  float flc = floorf(rc.y), cec = ceilf(rc.y);
  float wfr = 1.0f - (rc.x - flr);
  float wcr = 1.0f - (cer - rc.x);
  float wfc = 1.0f - (rc.y - flc);
  float wcc = 1.0f - (cec - rc.y);
  float xf = x[(size_t)((int)flr) * BB + lane];
  float xc = x[(size_t)((int)cer) * BB + lane];
  float inner = fmaf(wfr, xf, wcr * xc);
  atomicAdd(&out[(size_t)((int)flc) * BB + lane], v * wfc * inner);
  atomicAdd(&out[(size_t)((int)cec) * BB + lane], v * wcc * inner);
}

// ---------------------------------------------------------------------------
extern "C" void kernel_launch(void* const* d_in, const int* in_sizes, int n_in,
                              void* d_out, int out_size, void* d_ws, size_t ws_size,
                              hipStream_t stream) {
  const float2* ind = (const float2*)d_in[0];   // [N,2] f32
  const float*  val = (const float*)d_in[1];    // [N]   f32
  const float*  x   = (const float*)d_in[2];    // [D_IN*B] f32
  float* out = (float*)d_out;                   // [D_OUT*B] f32
  const int N = in_sizes[1];

  const size_t bin_bytes = (size_t)NBLK * D_OUT * CAP * sizeof(uint2);  // 50.3 MB
  const size_t cc_bytes  = (size_t)NBLK * D_OUT * sizeof(uint32_t);     // 1 MB
  const size_t xp_bytes  = (size_t)D_IN * BB * sizeof(float2);          // 2 MB
  const size_t ac_bytes  = (size_t)D_OUT * BB * sizeof(float);          // 1 MB

  if (N <= NBLK * PPB &&
      ws_size >= bin_bytes + cc_bytes + xp_bytes + 2 * ac_bytes) {
    char* w = (char*)d_ws;
    uint2*    bins    = (uint2*)w;      w += bin_bytes;
    uint32_t* cellCnt = (uint32_t*)w;   w += cc_bytes;
    float2*   xP      = (float2*)w;     w += xp_bytes;
    float*    accT    = (float*)w;      w += ac_bytes;
    float*    accN    = (float*)w;

    binprep_kernel<<<NBLK + (D_IN * BB + 255) / 256, 256, 0, stream>>>(
        ind, val, x, bins, cellCnt, xP, N);
    accum_kernel<<<D_OUT, 256, 0, stream>>>(cellCnt, bins, xP, accT, accN);
    combine_kernel<<<(D_OUT * BB) / 256, 256, 0, stream>>>(accT, accN, out);
  } else {
    (void)hipMemsetAsync(out, 0, (size_t)out_size * sizeof(float), stream);
    direct_kernel<<<(N + 3) / 4, 256, 0, stream>>>(ind, val, x, out, N);
  }
}